// Round 3
// baseline (1426.941 us; speedup 1.0000x reference)
//
#include <hip/hip_runtime.h>

#define TT 2048
#define FF 12
#define HH 96
#define CH 128
#define NT 768
#define L2E 1.44269504088896340736f

typedef __attribute__((ext_vector_type(2))) float f2;
typedef __attribute__((ext_vector_type(4))) float f4;

__device__ __forceinline__ float fast_exp2(float x){ return __builtin_amdgcn_exp2f(x); }
__device__ __forceinline__ float fast_rcp(float x){ return __builtin_amdgcn_rcpf(x); }

// 12 waves. Wave w owns h-indices [8w, 8w+8). Lane l: kh=l>>5 (K-half),
// gt=(l&31)>>3 (gate type i,f,g,o), hq=l&7, ht=8w+hq, gate row g=gt*96+ht.
// Per lane: 60-elem K-slice of v=[h(96)|x(21)+pad3] in 60 VGPRs.
// Per step: dot(60) -> shfl_xor(32) K-reduce -> activate -> shfl_xor-gather
// i,f,g,o -> redundant c/h update -> 8 lanes/wave write h. ONE barrier/step.
__global__ __launch_bounds__(NT, 3) void lstm_persist(
  const float* __restrict__ seq, const int* __restrict__ ev, const int* __restrict__ rsi,
  const int* __restrict__ len, const float* __restrict__ eemb, const float* __restrict__ remb,
  const float* __restrict__ W_ih, const float* __restrict__ W_hh,
  const float* __restrict__ b_ih, const float* __restrict__ b_hh,
  const float* __restrict__ W_mlp, const float* __restrict__ b_mlp,
  const float* __restrict__ W_fc, const float* __restrict__ b_fc,
  float* __restrict__ out)
{
  const int b   = blockIdx.x;
  const int tid = threadIdx.x;
  const int w   = tid >> 6;
  const int l   = tid & 63;
  const int kh  = l >> 5;
  const int lh  = l & 31;
  const int gt  = lh >> 3;
  const int hq  = lh & 7;
  const int ht  = 8*w + hq;          // 0..95
  const int g   = gt*96 + ht;        // 0..383

  __shared__ __align__(16) float hbuf[2][96];
  __shared__ __align__(16) float xch[CH][32];
  __shared__ __align__(16) float lastk[3*HH];
  __shared__ __align__(16) float tmp[192];
  __shared__ __align__(16) float h2[2*HH];
  __shared__ __align__(16) float et[32*6];
  __shared__ __align__(16) float rt[8*3];
  __shared__ int evb[CH];
  __shared__ int rsb[CH];

  // ---- prologue: per-lane weight K-slice (60 floats as 30 float2) ----
  f2 w2[30];
  #pragma unroll
  for (int j = 0; j < 30; ++j) {
    float v0, v1;
    const int c0 = kh*60 + 2*j;
    v0 = (c0 < 96) ? W_hh[g*96 + c0] : ((c0 < 117) ? W_ih[g*21 + (c0-96)] : 0.f);
    const int c1 = c0 + 1;
    v1 = (c1 < 96) ? W_hh[g*96 + c1] : ((c1 < 117) ? W_ih[g*21 + (c1-96)] : 0.f);
    w2[j] = (f2){v0, v1};
  }
  const float bg = b_ih[g] + b_hh[g];

  for (int i = tid; i < 2*HH; i += NT) hbuf[0][i] = 0.f;  // zero both buffers
  for (int i = tid; i < 3*HH; i += NT) lastk[i] = 0.f;
  for (int i = tid; i < 192;  i += NT) et[i] = eemb[i];
  for (int i = tid; i < 24;   i += NT) rt[i] = remb[i];

  float c_state = 0.f;
  const int L = len[b];

  for (int t0 = 0; t0 < L; t0 += CH) {
    // ---- stage x chunk (coalesced) ----
    for (int q = tid; q < CH*FF; q += NT) {
      const int r = q / 12;
      const int c = q - r*12;
      xch[r][c] = seq[(size_t)b*(TT*FF) + (size_t)t0*FF + q];
    }
    if (tid < CH) {
      evb[tid] = ev [b*TT + t0 + tid];
      rsb[tid] = rsi[b*TT + t0 + tid];
    }
    __syncthreads();
    for (int q = tid; q < CH*20; q += NT) {
      const int r  = q / 20;
      const int cc = q - r*20 + 12;
      float val;
      if (cc < 18)      val = et[evb[r]*6 + (cc-12)];
      else if (cc < 21) val = rt[rsb[r]*3 + (cc-18)];
      else              val = 0.f;
      xch[r][cc] = val;
    }
    __syncthreads();

    const int nr = min(CH, L - t0);
    for (int r = 0; r < nr; ++r) {
      const int t   = t0 + r;
      const int cur = t & 1;
      const float* hb = &hbuf[cur][0];
      const float* xr = &xch[r][0];
      // v-slice reads: j=0..8 from A (h part), j=9..14 from Bv (h tail / x)
      const f4* A  = (const f4*)(hb + kh*60);
      const f4* Bv = kh ? (const f4*)xr : ((const f4*)hb) + 9;

      f2 acc = (f2){0.f, 0.f};
      #pragma unroll
      for (int j = 0; j < 9; ++j) {
        const f4 q = A[j];
        acc = w2[2*j]   * q.xy + acc;
        acc = w2[2*j+1] * q.zw + acc;
      }
      #pragma unroll
      for (int j = 9; j < 15; ++j) {
        const f4 q = Bv[j-9];
        acc = w2[2*j]   * q.xy + acc;
        acc = w2[2*j+1] * q.zw + acc;
      }
      float p = acc.x + acc.y;
      p += __shfl_xor(p, 32);          // K-reduce across halves
      const float s = p + bg;

      // activation: gt==2 -> tanh, else sigmoid
      const bool is_t = (gt == 2);
      const float arg = is_t ? (-2.f*L2E)*fabsf(s) : (-L2E)*s;
      const float e   = fast_exp2(arg);
      const float r1  = fast_rcp(1.f + e);
      const float a0  = is_t ? copysignf((1.f - e)*r1, s) : r1;

      // gather i,f,g,o across gate-type lanes (xor within the 32-half)
      const float a1 = __shfl_xor(a0, 8);    // gt^1
      const float a2 = __shfl_xor(a0, 16);   // gt^2
      const float a3 = __shfl_xor(a0, 24);   // gt^3
      const float gi = (gt==0) ? a0 : (gt==1) ? a1 : (gt==2) ? a2 : a3;
      const float gf = (gt==1) ? a0 : (gt==0) ? a1 : (gt==3) ? a2 : a3;
      const float gg = (gt==2) ? a0 : (gt==3) ? a1 : (gt==0) ? a2 : a3;
      const float go = (gt==3) ? a0 : (gt==2) ? a1 : (gt==1) ? a2 : a3;

      c_state = fmaf(gf, c_state, gi*gg);
      const float e2 = fast_exp2((-2.f*L2E)*fabsf(c_state));
      const float th = copysignf((1.f - e2)*fast_rcp(1.f + e2), c_state);
      const float hn = go * th;

      if (l < 8) {                      // kh==0 && gt==0
        hbuf[cur ^ 1][ht] = hn;
        const int kk = t + 3 - L;
        if (kk >= 0) lastk[kk*96 + ht] = hn;
      }
      __syncthreads();                  // ONE barrier per step
    }
  }

  // ---- epilogue ----
  const float* hfin = &hbuf[L & 1][0];
  if (tid < 192) {
    const int hh = tid / 96;
    const int m  = tid - hh*96;
    const float* wp = W_mlp + m*288 + hh*144;
    const float* xp = lastk + hh*144;
    float s = 0.f;
    #pragma unroll 8
    for (int i = 0; i < 144; ++i) s = fmaf(wp[i], xp[i], s);
    tmp[tid] = s;
  }
  __syncthreads();
  if (tid < 96) {
    const float hl = tmp[tid] + tmp[96+tid] + b_mlp[tid];
    h2[96 + tid] = fmaxf(hl, 0.f);
    h2[tid] = hfin[tid];
  }
  __syncthreads();
  if (tid < 128) {
    const int o  = tid >> 6;
    const int ll = tid & 63;
    const float* wf = W_fc + o*192 + 3*ll;
    float s = fmaf(wf[0], h2[3*ll+0], fmaf(wf[1], h2[3*ll+1], wf[2]*h2[3*ll+2]));
    #pragma unroll
    for (int off = 32; off > 0; off >>= 1) s += __shfl_down(s, off);
    if (ll == 0) out[b*2 + o] = s + b_fc[o];
  }
}

extern "C" void kernel_launch(void* const* d_in, const int* in_sizes, int n_in,
                              void* d_out, int out_size, void* d_ws, size_t ws_size,
                              hipStream_t stream) {
  const float* seq   = (const float*)d_in[0];
  const int*   ev    = (const int*)  d_in[1];
  const int*   rsi   = (const int*)  d_in[2];
  const int*   len   = (const int*)  d_in[3];
  const float* eemb  = (const float*)d_in[4];
  const float* remb  = (const float*)d_in[5];
  const float* W_ih  = (const float*)d_in[6];
  const float* W_hh  = (const float*)d_in[7];
  const float* b_ih  = (const float*)d_in[8];
  const float* b_hh  = (const float*)d_in[9];
  const float* W_mlp = (const float*)d_in[10];
  const float* b_mlp = (const float*)d_in[11];
  const float* W_fc  = (const float*)d_in[12];
  const float* b_fc  = (const float*)d_in[13];

  hipLaunchKernelGGL(lstm_persist, dim3(256), dim3(NT), 0, stream,
                     seq, ev, rsi, len, eemb, remb, W_ih, W_hh, b_ih, b_hh,
                     W_mlp, b_mlp, W_fc, b_fc, (float*)d_out);
}